// Round 2
// baseline (1036.723 us; speedup 1.0000x reference)
//
#include <hip/hip_runtime.h>

// Problem constants (from reference setup_inputs)
constexpr int NB = 32;      // batch
constexpr int NN = 4096;    // nodes
constexpr int NE = 16384;   // edges
constexpr int NOUT = 76;    // 64 v1 outputs + 12 adv outputs
constexpr int NPART = NN / 2;  // 2048 split-K partial rows from k_gemm2h

__device__ __forceinline__ float relu_(float x) { return fmaxf(x, 0.0f); }

// ---------------------------------------------------------------- init
__global__ void k_init(float* deg, int* cnt, int* fill) {
  int i = blockIdx.x * 256 + threadIdx.x;
  if (i < NN) { deg[i] = 1.0f; cnt[i] = 0; fill[i] = 0; }  // deg starts at self-loop weight 1
}

// ---------------------------------------------------------------- edge pass 1: degree + counts
__global__ void k_edge1(const int* __restrict__ ei, const float* __restrict__ ew,
                        float* deg, int* cnt) {
  int e = blockIdx.x * 256 + threadIdx.x;
  if (e < NE) {
    int d = ei[NE + e];
    atomicAdd(&deg[d], ew[e]);
    atomicAdd(&cnt[d], 1);
  }
}

// ---------------------------------------------------------------- scan: csr offsets + dinv
__global__ void k_scan(const float* __restrict__ deg, float* __restrict__ dinv,
                       const int* __restrict__ cnt, int* __restrict__ csr_off) {
  __shared__ int sd[1024];
  int t = threadIdx.x;
  int base = t * 4;
  int c0 = cnt[base], c1 = cnt[base+1], c2 = cnt[base+2], c3 = cnt[base+3];
  int s = c0 + c1 + c2 + c3;
  sd[t] = s;
  __syncthreads();
  for (int off = 1; off < 1024; off <<= 1) {
    int v = (t >= off) ? sd[t - off] : 0;
    __syncthreads();
    sd[t] += v;
    __syncthreads();
  }
  int excl = sd[t] - s;
  csr_off[base]     = excl;
  csr_off[base + 1] = excl + c0;
  csr_off[base + 2] = excl + c0 + c1;
  csr_off[base + 3] = excl + c0 + c1 + c2;
  if (t == 1023) csr_off[4096] = sd[1023];
  for (int i = base; i < base + 4; ++i) dinv[i] = rsqrtf(deg[i]);
}

// ---------------------------------------------------------------- edge pass 2: fill CSR with normalized weights
__global__ void k_fill(const int* __restrict__ ei, const float* __restrict__ ew,
                       const float* __restrict__ dinv, const int* __restrict__ csr_off,
                       int* fill, int* __restrict__ csr_src, float* __restrict__ csr_w) {
  int e = blockIdx.x * 256 + threadIdx.x;
  if (e < NE) {
    int s = ei[e], d = ei[NE + e];
    float wn = ew[e] * dinv[s] * dinv[d];
    int p = csr_off[d] + atomicAdd(&fill[d], 1);
    csr_src[p] = s;
    csr_w[p] = wn;
  }
}

// ---------------------------------------------------------------- g0 = agg(x), 16 features
__global__ __launch_bounds__(256) void k_agg16(
    const float* __restrict__ x, const float* __restrict__ dinv,
    const int* __restrict__ csr_off, const int* __restrict__ csr_src,
    const float* __restrict__ csr_w, float* __restrict__ g0) {
  int b = blockIdx.y;
  int nn = threadIdx.x >> 4, f = threadIdx.x & 15;
  int n = blockIdx.x * 16 + nn;
  float di = dinv[n];
  size_t base = ((size_t)b * NN + n) * 16;
  float acc = x[base + f] * di * di;  // self term: h/deg
  int e0 = csr_off[n], e1 = csr_off[n + 1];
  for (int e = e0; e < e1; ++e)
    acc = fmaf(csr_w[e], x[((size_t)b * NN + csr_src[e]) * 16 + f], acc);
  g0[base + f] = acc;
}

// ---------------------------------------------------------------- h1 = relu(g0 @ W1 + b1)   [16 -> 128]
__global__ __launch_bounds__(256) void k_gemm1(
    const float* __restrict__ g0, const float* __restrict__ W1,
    const float* __restrict__ b1, float* __restrict__ h1) {
  __shared__ float W1s[16 * 128];
  __shared__ float g0s[256];
  int b = blockIdx.y, tile = blockIdx.x, t = threadIdx.x;
  for (int i = t; i < 2048; i += 256) W1s[i] = W1[i];
  g0s[t] = g0[((size_t)b * NN + tile * 16) * 16 + t];
  __syncthreads();
  int k = t & 127, ng = t >> 7;
  float wreg[16];
#pragma unroll
  for (int f = 0; f < 16; ++f) wreg[f] = W1s[f * 128 + k];
  float bias = b1[k];
#pragma unroll
  for (int nn = 0; nn < 8; ++nn) {
    int nl = ng * 8 + nn;
    float acc = bias;
#pragma unroll
    for (int f = 0; f < 16; ++f) acc = fmaf(g0s[nl * 16 + f], wreg[f], acc);
    h1[((size_t)b * NN + tile * 16 + nl) * 128 + k] = relu_(acc);
  }
}

// ---------------------------------------------------------------- g1 = agg(h1), 128 features
__global__ __launch_bounds__(256) void k_agg128(
    const float* __restrict__ h1, const float* __restrict__ dinv,
    const int* __restrict__ csr_off, const int* __restrict__ csr_src,
    const float* __restrict__ csr_w, float* __restrict__ g1) {
  int b = blockIdx.y;
  int nn = threadIdx.x >> 7, c = threadIdx.x & 127;
  int n = blockIdx.x * 2 + nn;
  float di = dinv[n];
  float acc = h1[((size_t)b * NN + n) * 128 + c] * di * di;
  int e0 = csr_off[n], e1 = csr_off[n + 1];
  for (int e = e0; e < e1; ++e)
    acc = fmaf(csr_w[e], h1[((size_t)b * NN + csr_src[e]) * 128 + c], acc);
  g1[((size_t)b * NN + n) * 128 + c] = acc;
}

// ---------------------------------------------------------------- fused: h2 = relu(g1 @ W2 + b2) [128->256]
// + dueling head partials: P[blk][b*76+o] = sum_{f in blk} h2[f][b] * W_head[f][o]
// block = 2 nodes (512 f) x 32 batches; 256 thr = 4 waves.
// gemm phase: jq=t&63 owns j=jq*4..+3; bg=t>>6 owns b=bg*8..+7  (per node)
// head phase: lane jq = output o (o<64: v1; lanes 0..11 also carry adv o=64+l); wave bg = b-group
// h2 tile parked in LDS [b][j] (stride 256): writes lane-contiguous float4 (conflict-free),
// reads wave-uniform broadcast float4 (conflict-free).
__global__ __launch_bounds__(256) void k_gemm2h(
    const float* __restrict__ g1, const float* __restrict__ W2,
    const float* __restrict__ b2, const float* __restrict__ v1W,
    const float* __restrict__ advW, float* __restrict__ P) {
  __shared__ float g1s[32 * 256];   // 32 KB: g1 rows for nodes n0,n0+1, all 32 b
  __shared__ float h2s[32 * 256];   // 32 KB: h2 tile for current node, [b][j]
  int t = threadIdx.x;
  int n0 = blockIdx.x * 2;
  for (int i = t; i < 8192; i += 256) {
    int b = i >> 8, r = i & 255;
    g1s[i] = g1[((size_t)b * NN + n0) * 128 + r];  // 256 floats = rows n0 and n0+1 back-to-back
  }
  __syncthreads();
  int jq = t & 63, bg = t >> 6, b0 = bg * 8;
  const float4* W2v = (const float4*)W2;
  const float2* g1s2 = (const float2*)g1s;
  float4 bv = ((const float4*)b2)[jq];
  float accv[8], acca[8];
#pragma unroll
  for (int i = 0; i < 8; ++i) { accv[i] = 0.0f; acca[i] = 0.0f; }
  bool adv_act = (jq < 12);
  for (int nn = 0; nn < 2; ++nn) {
    // ---- gemm phase: acc[bb][jj] = h2 pre-activation for (b=b0+bb, j=jq*4+jj)
    float acc[8][4];
#pragma unroll
    for (int bb = 0; bb < 8; ++bb) {
      acc[bb][0] = bv.x; acc[bb][1] = bv.y; acc[bb][2] = bv.z; acc[bb][3] = bv.w;
    }
    for (int c = 0; c < 128; c += 2) {
      float4 wA = W2v[c * 64 + jq];
      float4 wB = W2v[(c + 1) * 64 + jq];
#pragma unroll
      for (int bb = 0; bb < 8; ++bb) {
        float2 f2 = g1s2[(b0 + bb) * 128 + nn * 64 + (c >> 1)];
        acc[bb][0] = fmaf(wA.x, f2.x, acc[bb][0]); acc[bb][0] = fmaf(wB.x, f2.y, acc[bb][0]);
        acc[bb][1] = fmaf(wA.y, f2.x, acc[bb][1]); acc[bb][1] = fmaf(wB.y, f2.y, acc[bb][1]);
        acc[bb][2] = fmaf(wA.z, f2.x, acc[bb][2]); acc[bb][2] = fmaf(wB.z, f2.y, acc[bb][2]);
        acc[bb][3] = fmaf(wA.w, f2.x, acc[bb][3]); acc[bb][3] = fmaf(wB.w, f2.y, acc[bb][3]);
      }
    }
    // ---- park relu(h2) tile in LDS (wait for previous head phase's readers first)
    __syncthreads();
#pragma unroll
    for (int bb = 0; bb < 8; ++bb) {
      float4 hv;
      hv.x = relu_(acc[bb][0]); hv.y = relu_(acc[bb][1]);
      hv.z = relu_(acc[bb][2]); hv.w = relu_(acc[bb][3]);
      *(float4*)&h2s[(b0 + bb) * 256 + jq * 4] = hv;
    }
    __syncthreads();
    // ---- head phase: o = jq, b-range = b0..b0+7
    const float* v1Wn  = v1W  + (size_t)(n0 + nn) * 256 * 64 + jq;
    const float* advWn = advW + (size_t)(n0 + nn) * 256 * 12 + jq;
    for (int jc = 0; jc < 64; ++jc) {
      float wv0 = v1Wn[(jc * 4 + 0) * 64];
      float wv1 = v1Wn[(jc * 4 + 1) * 64];
      float wv2 = v1Wn[(jc * 4 + 2) * 64];
      float wv3 = v1Wn[(jc * 4 + 3) * 64];
      float wa0 = 0.0f, wa1 = 0.0f, wa2 = 0.0f, wa3 = 0.0f;
      if (adv_act) {
        wa0 = advWn[(jc * 4 + 0) * 12];
        wa1 = advWn[(jc * 4 + 1) * 12];
        wa2 = advWn[(jc * 4 + 2) * 12];
        wa3 = advWn[(jc * 4 + 3) * 12];
      }
#pragma unroll
      for (int bb = 0; bb < 8; ++bb) {
        float4 h = *(const float4*)&h2s[(b0 + bb) * 256 + jc * 4];  // broadcast
        accv[bb] = fmaf(h.x, wv0, accv[bb]);
        accv[bb] = fmaf(h.y, wv1, accv[bb]);
        accv[bb] = fmaf(h.z, wv2, accv[bb]);
        accv[bb] = fmaf(h.w, wv3, accv[bb]);
        acca[bb] = fmaf(h.x, wa0, acca[bb]);
        acca[bb] = fmaf(h.y, wa1, acca[bb]);
        acca[bb] = fmaf(h.z, wa2, acca[bb]);
        acca[bb] = fmaf(h.w, wa3, acca[bb]);
      }
    }
  }
  // ---- write per-block partials: P[blk][b*76 + o], lane-contiguous in o
  float* Pb = P + (size_t)blockIdx.x * (NB * NOUT);
#pragma unroll
  for (int bb = 0; bb < 8; ++bb) {
    Pb[(b0 + bb) * NOUT + jq] = accv[bb];
    if (adv_act) Pb[(b0 + bb) * NOUT + 64 + jq] = acca[bb];
  }
}

// ---------------------------------------------------------------- reduce stage 1: 2048 -> 128 partials
__global__ __launch_bounds__(256) void k_red1(const float* __restrict__ P,
                                              float* __restrict__ P1) {
  int r = blockIdx.x, t = threadIdx.x;
  const float* p = P + (size_t)r * 16 * (NB * NOUT);
  for (int o = t; o < NB * NOUT; o += 256) {
    float s = 0.0f;
    for (int k = 0; k < 16; ++k) s += p[(size_t)k * (NB * NOUT) + o];
    P1[r * (NB * NOUT) + o] = s;
  }
}

// ---------------------------------------------------------------- reduce stage 2: 128 -> 1
__global__ __launch_bounds__(256) void k_red2(const float* __restrict__ P1,
                                              float* __restrict__ S) {
  int o = blockIdx.x * 256 + threadIdx.x;
  if (o >= NB * NOUT) return;
  float s = 0.0f;
  for (int r = 0; r < 128; ++r) s += P1[(size_t)r * (NB * NOUT) + o];
  S[o] = s;
}

// ---------------------------------------------------------------- final MLP + dueling combine
__global__ void k_final(const float* __restrict__ S,
                        const float* __restrict__ v1b, const float* __restrict__ v2W,
                        const float* __restrict__ v2b, const float* __restrict__ v3W,
                        const float* __restrict__ v3b, const float* __restrict__ advb,
                        float* __restrict__ out) {
  int b = blockIdx.x, t = threadIdx.x;
  __shared__ float v1s[64], v2s[64], as_[12];
  __shared__ float v3s;
  v1s[t] = relu_(S[b * NOUT + t] + v1b[t]);
  if (t < 12) as_[t] = relu_(S[b * NOUT + 64 + t] + advb[t]);
  __syncthreads();
  float acc = v2b[t];
  for (int k = 0; k < 64; ++k) acc = fmaf(v1s[k], v2W[k * 64 + t], acc);
  v2s[t] = relu_(acc);
  __syncthreads();
  if (t == 0) {
    float v3 = v3b[0];
    for (int j = 0; j < 64; ++j) v3 = fmaf(v2s[j], v3W[j], v3);
    v3s = v3;
  }
  __syncthreads();
  if (t < 12) {
    int h = t >> 2;
    float m = 0.25f * (as_[h * 4] + as_[h * 4 + 1] + as_[h * 4 + 2] + as_[h * 4 + 3]);
    out[b * 12 + t] = v3s + as_[t] - m;
  }
}

// ================================================================ launcher
extern "C" void kernel_launch(void* const* d_in, const int* in_sizes, int n_in,
                              void* d_out, int out_size, void* d_ws, size_t ws_size,
                              hipStream_t stream) {
  (void)in_sizes; (void)n_in; (void)out_size; (void)ws_size;
  const float* x    = (const float*)d_in[0];
  const int*   ei   = (const int*)d_in[1];
  const float* ew   = (const float*)d_in[2];
  const float* W1   = (const float*)d_in[3];
  const float* b1   = (const float*)d_in[4];
  const float* W2   = (const float*)d_in[5];
  const float* b2   = (const float*)d_in[6];
  const float* advW = (const float*)d_in[7];
  const float* advb = (const float*)d_in[8];
  const float* v1W  = (const float*)d_in[9];
  const float* v1b  = (const float*)d_in[10];
  const float* v2W  = (const float*)d_in[11];
  const float* v2b  = (const float*)d_in[12];
  const float* v3W  = (const float*)d_in[13];
  const float* v3b  = (const float*)d_in[14];
  float* out = (float*)d_out;

  char* w8 = (char*)d_ws;
  // small region [0, 1 MB)
  float* deg     = (float*)w8;                 // 4096
  float* dinv    = deg + 4096;                 // 4096
  int*   csr_off = (int*)(dinv + 4096);        // 4097 (padded to 4352)
  int*   cnt     = csr_off + 4352;             // 4096
  int*   fill    = cnt + 4096;                 // 4096
  int*   csr_src = fill + 4096;                // 16384
  float* csr_w   = (float*)(csr_src + NE);     // 16384
  float* S       = csr_w + NE;                 // 2432
  // big buffers
  float* P  = (float*)(w8 + (size_t)1  * 1024 * 1024);  // 2048*2432*4 ≈ 19 MB  [1..21 MB)
  float* P1 = (float*)(w8 + (size_t)21 * 1024 * 1024);  // 128*2432*4 ≈ 1.24 MB [21..23 MB)
  float* g0 = (float*)(w8 + (size_t)24 * 1024 * 1024);  // 8 MB   [24..32 MB)
  float* g1 = (float*)(w8 + (size_t)32 * 1024 * 1024);  // 64 MB  [32..96 MB)
  float* h1 = (float*)(w8 + (size_t)96 * 1024 * 1024);  // 64 MB  [96..160 MB)

  k_init   <<<16, 256, 0, stream>>>(deg, cnt, fill);
  k_edge1  <<<64, 256, 0, stream>>>(ei, ew, deg, cnt);
  k_scan   <<<1, 1024, 0, stream>>>(deg, dinv, cnt, csr_off);
  k_fill   <<<64, 256, 0, stream>>>(ei, ew, dinv, csr_off, fill, csr_src, csr_w);
  k_agg16  <<<dim3(NN / 16, NB), 256, 0, stream>>>(x, dinv, csr_off, csr_src, csr_w, g0);
  k_gemm1  <<<dim3(NN / 16, NB), 256, 0, stream>>>(g0, W1, b1, h1);
  k_agg128 <<<dim3(NN / 2, NB), 256, 0, stream>>>(h1, dinv, csr_off, csr_src, csr_w, g1);
  k_gemm2h <<<NN / 2, 256, 0, stream>>>(g1, W2, b2, v1W, advW, P);
  k_red1   <<<128, 256, 0, stream>>>(P, P1);
  k_red2   <<<10, 256, 0, stream>>>(P1, S);
  k_final  <<<NB, 64, 0, stream>>>(S, v1b, v2W, v2b, v3W, v3b, advb, out);
}

// Round 3
// 801.935 us; speedup vs baseline: 1.2928x; 1.2928x over previous
//
#include <hip/hip_runtime.h>

// Problem constants (from reference setup_inputs)
constexpr int NB = 32;      // batch
constexpr int NN = 4096;    // nodes
constexpr int NE = 16384;   // edges
constexpr int NOUT_PAD = 2432;  // 32*(64 v1) + 32*(12 adv) partial row size

__device__ __forceinline__ float relu_(float x) { return fmaxf(x, 0.0f); }

// ---------------------------------------------------------------- init
__global__ void k_init(float* deg, int* cnt, int* fill) {
  int i = blockIdx.x * 256 + threadIdx.x;
  if (i < NN) { deg[i] = 1.0f; cnt[i] = 0; fill[i] = 0; }  // deg starts at self-loop weight 1
}

// ---------------------------------------------------------------- edge pass 1: degree + counts
__global__ void k_edge1(const int* __restrict__ ei, const float* __restrict__ ew,
                        float* deg, int* cnt) {
  int e = blockIdx.x * 256 + threadIdx.x;
  if (e < NE) {
    int d = ei[NE + e];
    atomicAdd(&deg[d], ew[e]);
    atomicAdd(&cnt[d], 1);
  }
}

// ---------------------------------------------------------------- scan: csr offsets + dinv
__global__ void k_scan(const float* __restrict__ deg, float* __restrict__ dinv,
                       const int* __restrict__ cnt, int* __restrict__ csr_off) {
  __shared__ int sd[1024];
  int t = threadIdx.x;
  int base = t * 4;
  int c0 = cnt[base], c1 = cnt[base+1], c2 = cnt[base+2], c3 = cnt[base+3];
  int s = c0 + c1 + c2 + c3;
  sd[t] = s;
  __syncthreads();
  for (int off = 1; off < 1024; off <<= 1) {
    int v = (t >= off) ? sd[t - off] : 0;
    __syncthreads();
    sd[t] += v;
    __syncthreads();
  }
  int excl = sd[t] - s;
  csr_off[base]     = excl;
  csr_off[base + 1] = excl + c0;
  csr_off[base + 2] = excl + c0 + c1;
  csr_off[base + 3] = excl + c0 + c1 + c2;
  if (t == 1023) csr_off[4096] = sd[1023];
  for (int i = base; i < base + 4; ++i) dinv[i] = rsqrtf(deg[i]);
}

// ---------------------------------------------------------------- edge pass 2: fill CSR with normalized weights
__global__ void k_fill(const int* __restrict__ ei, const float* __restrict__ ew,
                       const float* __restrict__ dinv, const int* __restrict__ csr_off,
                       int* fill, int* __restrict__ csr_src, float* __restrict__ csr_w) {
  int e = blockIdx.x * 256 + threadIdx.x;
  if (e < NE) {
    int s = ei[e], d = ei[NE + e];
    float wn = ew[e] * dinv[s] * dinv[d];
    int p = csr_off[d] + atomicAdd(&fill[d], 1);
    csr_src[p] = s;
    csr_w[p] = wn;
  }
}

// ---------------------------------------------------------------- g0 = agg(x), 16 features
__global__ __launch_bounds__(256) void k_agg16(
    const float* __restrict__ x, const float* __restrict__ dinv,
    const int* __restrict__ csr_off, const int* __restrict__ csr_src,
    const float* __restrict__ csr_w, float* __restrict__ g0) {
  int b = blockIdx.y;
  int nn = threadIdx.x >> 4, f = threadIdx.x & 15;
  int n = blockIdx.x * 16 + nn;
  float di = dinv[n];
  size_t base = ((size_t)b * NN + n) * 16;
  float acc = x[base + f] * di * di;  // self term: h/deg
  int e0 = csr_off[n], e1 = csr_off[n + 1];
  for (int e = e0; e < e1; ++e)
    acc = fmaf(csr_w[e], x[((size_t)b * NN + csr_src[e]) * 16 + f], acc);
  g0[base + f] = acc;
}

// ---------------------------------------------------------------- h1 = relu(g0 @ W1 + b1)   [16 -> 128]
__global__ __launch_bounds__(256) void k_gemm1(
    const float* __restrict__ g0, const float* __restrict__ W1,
    const float* __restrict__ b1, float* __restrict__ h1) {
  __shared__ float W1s[16 * 128];
  __shared__ float g0s[256];
  int b = blockIdx.y, tile = blockIdx.x, t = threadIdx.x;
  for (int i = t; i < 2048; i += 256) W1s[i] = W1[i];
  g0s[t] = g0[((size_t)b * NN + tile * 16) * 16 + t];
  __syncthreads();
  int k = t & 127, ng = t >> 7;
  float wreg[16];
#pragma unroll
  for (int f = 0; f < 16; ++f) wreg[f] = W1s[f * 128 + k];
  float bias = b1[k];
#pragma unroll
  for (int nn = 0; nn < 8; ++nn) {
    int nl = ng * 8 + nn;
    float acc = bias;
#pragma unroll
    for (int f = 0; f < 16; ++f) acc = fmaf(g0s[nl * 16 + f], wreg[f], acc);
    h1[((size_t)b * NN + tile * 16 + nl) * 128 + k] = relu_(acc);
  }
}

// ---------------------------------------------------------------- g1 = agg(h1), 128 features
__global__ __launch_bounds__(256) void k_agg128(
    const float* __restrict__ h1, const float* __restrict__ dinv,
    const int* __restrict__ csr_off, const int* __restrict__ csr_src,
    const float* __restrict__ csr_w, float* __restrict__ g1) {
  int b = blockIdx.y;
  int nn = threadIdx.x >> 7, c = threadIdx.x & 127;
  int n = blockIdx.x * 2 + nn;
  float di = dinv[n];
  float acc = h1[((size_t)b * NN + n) * 128 + c] * di * di;
  int e0 = csr_off[n], e1 = csr_off[n + 1];
  for (int e = e0; e < e1; ++e)
    acc = fmaf(csr_w[e], h1[((size_t)b * NN + csr_src[e]) * 128 + c], acc);
  g1[((size_t)b * NN + n) * 128 + c] = acc;
}

// ---------------------------------------------------------------- h2T[f][b] = relu(g1 @ W2 + b2)  [128 -> 256], transposed store
// block: 2 nodes x all 32 batches; 256 thr = 4 waves; thread: jq=t&63 (4 j's), bg=t>>6 (8 b's)
__global__ __launch_bounds__(256) void k_gemm2(
    const float* __restrict__ g1, const float* __restrict__ W2,
    const float* __restrict__ b2, float* __restrict__ h2T) {
  __shared__ float g1s[32 * 256];
  int t = threadIdx.x;
  int n0 = blockIdx.x * 2;
  for (int i = t; i < 8192; i += 256) {
    int b = i >> 8, r = i & 255;
    g1s[i] = g1[((size_t)b * NN + n0) * 128 + r];
  }
  __syncthreads();
  int jq = t & 63, bg = t >> 6, b0 = bg * 8;
  const float4* W2v = (const float4*)W2;
  const float2* g1s2 = (const float2*)g1s;
  float4 bv = ((const float4*)b2)[jq];
  for (int nn = 0; nn < 2; ++nn) {
    float acc[8][4];
#pragma unroll
    for (int bb = 0; bb < 8; ++bb) {
      acc[bb][0] = bv.x; acc[bb][1] = bv.y; acc[bb][2] = bv.z; acc[bb][3] = bv.w;
    }
    for (int c = 0; c < 128; c += 2) {
      float4 wA = W2v[c * 64 + jq];
      float4 wB = W2v[(c + 1) * 64 + jq];
#pragma unroll
      for (int bb = 0; bb < 8; ++bb) {
        float2 f2 = g1s2[(b0 + bb) * 128 + nn * 64 + (c >> 1)];
        acc[bb][0] = fmaf(wA.x, f2.x, acc[bb][0]); acc[bb][0] = fmaf(wB.x, f2.y, acc[bb][0]);
        acc[bb][1] = fmaf(wA.y, f2.x, acc[bb][1]); acc[bb][1] = fmaf(wB.y, f2.y, acc[bb][1]);
        acc[bb][2] = fmaf(wA.z, f2.x, acc[bb][2]); acc[bb][2] = fmaf(wB.z, f2.y, acc[bb][2]);
        acc[bb][3] = fmaf(wA.w, f2.x, acc[bb][3]); acc[bb][3] = fmaf(wB.w, f2.y, acc[bb][3]);
      }
    }
#pragma unroll
    for (int jj = 0; jj < 4; ++jj) {
      float4 lo, hi;
      lo.x = relu_(acc[0][jj]); lo.y = relu_(acc[1][jj]); lo.z = relu_(acc[2][jj]); lo.w = relu_(acc[3][jj]);
      hi.x = relu_(acc[4][jj]); hi.y = relu_(acc[5][jj]); hi.z = relu_(acc[6][jj]); hi.w = relu_(acc[7][jj]);
      float* dst0 = h2T + ((size_t)(n0 + nn) * 256 + jq * 4 + jj) * 32 + b0;
      *(float4*)dst0 = lo;
      *(float4*)(dst0 + 4) = hi;
    }
  }
}

// ---------------------------------------------------------------- head v2: per-block (256 f) partials of feat@v1W, feat@advW
// block = 256 f staged in LDS [fl][b] (32 KB, coalesced float4 in, broadcast float4 out).
// wave w: f = f0 + w*64 + i (64 f, contiguous). lane l: o=l for v1; o=64+l for adv (l<12).
// weight loads: one coalesced 256 B v1W row + one 48 B advW row per f per wave.
// P[n][b*64+l] (v) and P[n][2048 + b*12+l] (adv), n = blockIdx.x.
__global__ __launch_bounds__(256) void k_head(
    const float* __restrict__ h2T, const float* __restrict__ v1W,
    const float* __restrict__ advW, float* __restrict__ P) {
  __shared__ float s[8192];  // feat staging, then cross-wave reduction
  int t = threadIdx.x;
  size_t f0 = (size_t)blockIdx.x * 256;
  const float4* src = (const float4*)(h2T + f0 * 32);
  float4* dst = (float4*)s;
#pragma unroll
  for (int i = 0; i < 8; ++i) dst[t + 256 * i] = src[t + 256 * i];
  __syncthreads();
  int l = t & 63, w = t >> 6;
  bool adv_act = (l < 12);
  float accv[32], acca[32];
#pragma unroll
  for (int i = 0; i < 32; ++i) { accv[i] = 0.0f; acca[i] = 0.0f; }
  const float* v1p  = v1W  + (f0 + (size_t)w * 64) * 64 + l;
  const float* advp = advW + (f0 + (size_t)w * 64) * 12 + l;
#pragma unroll 2
  for (int i = 0; i < 64; ++i) {
    float wv = v1p[i * 64];
    float wa = adv_act ? advp[i * 12] : 0.0f;
    const float4* fr = (const float4*)&s[(w * 64 + i) * 32];
#pragma unroll
    for (int bb = 0; bb < 8; ++bb) {
      float4 h = fr[bb];  // LDS broadcast, conflict-free
      accv[4 * bb + 0] = fmaf(h.x, wv, accv[4 * bb + 0]);
      accv[4 * bb + 1] = fmaf(h.y, wv, accv[4 * bb + 1]);
      accv[4 * bb + 2] = fmaf(h.z, wv, accv[4 * bb + 2]);
      accv[4 * bb + 3] = fmaf(h.w, wv, accv[4 * bb + 3]);
      acca[4 * bb + 0] = fmaf(h.x, wa, acca[4 * bb + 0]);
      acca[4 * bb + 1] = fmaf(h.y, wa, acca[4 * bb + 1]);
      acca[4 * bb + 2] = fmaf(h.z, wa, acca[4 * bb + 2]);
      acca[4 * bb + 3] = fmaf(h.w, wa, acca[4 * bb + 3]);
    }
  }
  float* Pb = P + (size_t)blockIdx.x * NOUT_PAD;
  // cross-wave reduce: v-part (4 waves x 2048 = 8192 floats, exactly fits s)
  __syncthreads();
#pragma unroll
  for (int b = 0; b < 32; ++b) s[w * 2048 + b * 64 + l] = accv[b];
  __syncthreads();
  for (int o = t; o < 2048; o += 256)
    Pb[o] = s[o] + s[2048 + o] + s[4096 + o] + s[6144 + o];
  __syncthreads();
  // adv part (4 waves x 384)
  if (adv_act) {
#pragma unroll
    for (int b = 0; b < 32; ++b) s[w * 384 + b * 12 + l] = acca[b];
  }
  __syncthreads();
  for (int o = t; o < 384; o += 256)
    Pb[2048 + o] = s[o] + s[384 + o] + s[768 + o] + s[1152 + o];
}

// ---------------------------------------------------------------- reduce stage 1: 4096 -> 64 rows
__global__ __launch_bounds__(256) void k_red1(const float* __restrict__ P,
                                              float* __restrict__ P1) {
  int r = blockIdx.x, t = threadIdx.x;
  const float* p = P + (size_t)r * 64 * NOUT_PAD;
  for (int o = t; o < NOUT_PAD; o += 256) {
    float sum = 0.0f;
    for (int k = 0; k < 64; ++k) sum += p[(size_t)k * NOUT_PAD + o];
    P1[r * NOUT_PAD + o] = sum;
  }
}

// ---------------------------------------------------------------- reduce stage 2: 64 -> 1
__global__ __launch_bounds__(256) void k_red2(const float* __restrict__ P1,
                                              float* __restrict__ S) {
  int o = blockIdx.x * 256 + threadIdx.x;
  if (o >= NOUT_PAD) return;
  float sum = 0.0f;
  for (int r = 0; r < 64; ++r) sum += P1[(size_t)r * NOUT_PAD + o];
  S[o] = sum;
}

// ---------------------------------------------------------------- final MLP + dueling combine
// S layout: S[b*64 + j] = v1 pre-bias (j<64); S[2048 + b*12 + j] = adv pre-bias
__global__ void k_final(const float* __restrict__ S,
                        const float* __restrict__ v1b, const float* __restrict__ v2W,
                        const float* __restrict__ v2b, const float* __restrict__ v3W,
                        const float* __restrict__ v3b, const float* __restrict__ advb,
                        float* __restrict__ out) {
  int b = blockIdx.x, t = threadIdx.x;
  __shared__ float v1s[64], v2s[64], as_[12];
  __shared__ float v3s;
  v1s[t] = relu_(S[b * 64 + t] + v1b[t]);
  if (t < 12) as_[t] = relu_(S[2048 + b * 12 + t] + advb[t]);
  __syncthreads();
  float acc = v2b[t];
  for (int k = 0; k < 64; ++k) acc = fmaf(v1s[k], v2W[k * 64 + t], acc);
  v2s[t] = relu_(acc);
  __syncthreads();
  if (t == 0) {
    float v3 = v3b[0];
    for (int j = 0; j < 64; ++j) v3 = fmaf(v2s[j], v3W[j], v3);
    v3s = v3;
  }
  __syncthreads();
  if (t < 12) {
    int h = t >> 2;
    float m = 0.25f * (as_[h * 4] + as_[h * 4 + 1] + as_[h * 4 + 2] + as_[h * 4 + 3]);
    out[b * 12 + t] = v3s + as_[t] - m;
  }
}

// ================================================================ launcher
extern "C" void kernel_launch(void* const* d_in, const int* in_sizes, int n_in,
                              void* d_out, int out_size, void* d_ws, size_t ws_size,
                              hipStream_t stream) {
  (void)in_sizes; (void)n_in; (void)out_size; (void)ws_size;
  const float* x    = (const float*)d_in[0];
  const int*   ei   = (const int*)d_in[1];
  const float* ew   = (const float*)d_in[2];
  const float* W1   = (const float*)d_in[3];
  const float* b1   = (const float*)d_in[4];
  const float* W2   = (const float*)d_in[5];
  const float* b2   = (const float*)d_in[6];
  const float* advW = (const float*)d_in[7];
  const float* advb = (const float*)d_in[8];
  const float* v1W  = (const float*)d_in[9];
  const float* v1b  = (const float*)d_in[10];
  const float* v2W  = (const float*)d_in[11];
  const float* v2b  = (const float*)d_in[12];
  const float* v3W  = (const float*)d_in[13];
  const float* v3b  = (const float*)d_in[14];
  float* out = (float*)d_out;

  const size_t MB = 1024 * 1024;
  char* w8 = (char*)d_ws;
  // small region [0, 1 MB)
  float* deg     = (float*)w8;                 // 4096
  float* dinv    = deg + 4096;                 // 4096
  int*   csr_off = (int*)(dinv + 4096);        // 4097 (padded to 4352)
  int*   cnt     = csr_off + 4352;             // 4096
  int*   fill    = cnt + 4096;                 // 4096
  int*   csr_src = fill + 4096;                // 16384
  float* csr_w   = (float*)(csr_src + NE);     // 16384
  float* S       = csr_w + NE;                 // 2432
  // big buffers with lifetime-based overlays (total footprint 196 MB):
  //   h1  [4,68)    written by gemm1, read by agg128
  //   g0  [68,76)   written by agg16, read by gemm1
  //   h2T [4,132)   written by gemm2 (h1,g0 dead), read by head
  //   g1  [132,196) written by agg128, read by gemm2
  //   P   [132,171) written by head (g1 dead), read by red1
  //   P1  [172,173) red1 -> red2
  float* h1  = (float*)(w8 + 4 * MB);
  float* g0  = (float*)(w8 + 68 * MB);
  float* h2T = (float*)(w8 + 4 * MB);
  float* g1  = (float*)(w8 + 132 * MB);
  float* P   = (float*)(w8 + 132 * MB);
  float* P1  = (float*)(w8 + 172 * MB);

  k_init  <<<16, 256, 0, stream>>>(deg, cnt, fill);
  k_edge1 <<<64, 256, 0, stream>>>(ei, ew, deg, cnt);
  k_scan  <<<1, 1024, 0, stream>>>(deg, dinv, cnt, csr_off);
  k_fill  <<<64, 256, 0, stream>>>(ei, ew, dinv, csr_off, fill, csr_src, csr_w);
  k_agg16 <<<dim3(NN / 16, NB), 256, 0, stream>>>(x, dinv, csr_off, csr_src, csr_w, g0);
  k_gemm1 <<<dim3(NN / 16, NB), 256, 0, stream>>>(g0, W1, b1, h1);
  k_agg128<<<dim3(NN / 2, NB), 256, 0, stream>>>(h1, dinv, csr_off, csr_src, csr_w, g1);
  k_gemm2 <<<NN / 2, 256, 0, stream>>>(g1, W2, b2, h2T);
  k_head  <<<NN, 256, 0, stream>>>(h2T, v1W, advW, P);
  k_red1  <<<64, 256, 0, stream>>>(P, P1);
  k_red2  <<<10, 256, 0, stream>>>(P1, S);
  k_final <<<NB, 64, 0, stream>>>(S, v1b, v2W, v2b, v3W, v3b, advb, out);
}

// Round 4
// 711.746 us; speedup vs baseline: 1.4566x; 1.1267x over previous
//
#include <hip/hip_runtime.h>
#include <hip/hip_bf16.h>

// Problem constants (from reference setup_inputs)
constexpr int NB = 32;      // batch
constexpr int NN = 4096;    // nodes
constexpr int NE = 16384;   // edges
constexpr int NOUT_PAD = 2432;  // 32*(64 v1) + 32*(12 adv) partial row size

typedef __attribute__((ext_vector_type(8))) short short8;    // 8 bf16 = 4 VGPRs (MFMA A/B frag)
typedef __attribute__((ext_vector_type(4))) float floatx4;   // MFMA C/D frag

__device__ __forceinline__ float relu_(float x) { return fmaxf(x, 0.0f); }
__device__ __forceinline__ unsigned short bf16_(float x) {
  __hip_bfloat16 h = __float2bfloat16(x);
  return __builtin_bit_cast(unsigned short, h);
}

// ---------------------------------------------------------------- init
__global__ void k_init(float* deg, int* cnt, int* fill) {
  int i = blockIdx.x * 256 + threadIdx.x;
  if (i < NN) { deg[i] = 1.0f; cnt[i] = 0; fill[i] = 0; }  // deg starts at self-loop weight 1
}

// ---------------------------------------------------------------- edge pass 1: degree + counts
__global__ void k_edge1(const int* __restrict__ ei, const float* __restrict__ ew,
                        float* deg, int* cnt) {
  int e = blockIdx.x * 256 + threadIdx.x;
  if (e < NE) {
    int d = ei[NE + e];
    atomicAdd(&deg[d], ew[e]);
    atomicAdd(&cnt[d], 1);
  }
}

// ---------------------------------------------------------------- scan: csr offsets + dinv
__global__ void k_scan(const float* __restrict__ deg, float* __restrict__ dinv,
                       const int* __restrict__ cnt, int* __restrict__ csr_off) {
  __shared__ int sd[1024];
  int t = threadIdx.x;
  int base = t * 4;
  int c0 = cnt[base], c1 = cnt[base+1], c2 = cnt[base+2], c3 = cnt[base+3];
  int s = c0 + c1 + c2 + c3;
  sd[t] = s;
  __syncthreads();
  for (int off = 1; off < 1024; off <<= 1) {
    int v = (t >= off) ? sd[t - off] : 0;
    __syncthreads();
    sd[t] += v;
    __syncthreads();
  }
  int excl = sd[t] - s;
  csr_off[base]     = excl;
  csr_off[base + 1] = excl + c0;
  csr_off[base + 2] = excl + c0 + c1;
  csr_off[base + 3] = excl + c0 + c1 + c2;
  if (t == 1023) csr_off[4096] = sd[1023];
  for (int i = base; i < base + 4; ++i) dinv[i] = rsqrtf(deg[i]);
}

// ---------------------------------------------------------------- edge pass 2: fill CSR with normalized weights
__global__ void k_fill(const int* __restrict__ ei, const float* __restrict__ ew,
                       const float* __restrict__ dinv, const int* __restrict__ csr_off,
                       int* fill, int* __restrict__ csr_src, float* __restrict__ csr_w) {
  int e = blockIdx.x * 256 + threadIdx.x;
  if (e < NE) {
    int s = ei[e], d = ei[NE + e];
    float wn = ew[e] * dinv[s] * dinv[d];
    int p = csr_off[d] + atomicAdd(&fill[d], 1);
    csr_src[p] = s;
    csr_w[p] = wn;
  }
}

// ---------------------------------------------------------------- W2T[j][c] = bf16(W2[c][j])
__global__ void k_prep(const float* __restrict__ W2, unsigned short* __restrict__ W2T) {
  int idx = blockIdx.x * 256 + threadIdx.x;  // 32768 = 256 j * 128 c
  int j = idx >> 7, c = idx & 127;
  W2T[idx] = bf16_(W2[c * 256 + j]);
}

// ---------------------------------------------------------------- g0 = agg(x), 16 features
__global__ __launch_bounds__(256) void k_agg16(
    const float* __restrict__ x, const float* __restrict__ dinv,
    const int* __restrict__ csr_off, const int* __restrict__ csr_src,
    const float* __restrict__ csr_w, float* __restrict__ g0) {
  int b = blockIdx.y;
  int nn = threadIdx.x >> 4, f = threadIdx.x & 15;
  int n = blockIdx.x * 16 + nn;
  float di = dinv[n];
  size_t base = ((size_t)b * NN + n) * 16;
  float acc = x[base + f] * di * di;  // self term: h/deg
  int e0 = csr_off[n], e1 = csr_off[n + 1];
  for (int e = e0; e < e1; ++e)
    acc = fmaf(csr_w[e], x[((size_t)b * NN + csr_src[e]) * 16 + f], acc);
  g0[base + f] = acc;
}

// ---------------------------------------------------------------- h1 = relu(g0 @ W1 + b1)   [16 -> 128]
__global__ __launch_bounds__(256) void k_gemm1(
    const float* __restrict__ g0, const float* __restrict__ W1,
    const float* __restrict__ b1, float* __restrict__ h1) {
  __shared__ float W1s[16 * 128];
  __shared__ float g0s[256];
  int b = blockIdx.y, tile = blockIdx.x, t = threadIdx.x;
  for (int i = t; i < 2048; i += 256) W1s[i] = W1[i];
  g0s[t] = g0[((size_t)b * NN + tile * 16) * 16 + t];
  __syncthreads();
  int k = t & 127, ng = t >> 7;
  float wreg[16];
#pragma unroll
  for (int f = 0; f < 16; ++f) wreg[f] = W1s[f * 128 + k];
  float bias = b1[k];
#pragma unroll
  for (int nn = 0; nn < 8; ++nn) {
    int nl = ng * 8 + nn;
    float acc = bias;
#pragma unroll
    for (int f = 0; f < 16; ++f) acc = fmaf(g0s[nl * 16 + f], wreg[f], acc);
    h1[((size_t)b * NN + tile * 16 + nl) * 128 + k] = relu_(acc);
  }
}

// ---------------------------------------------------------------- g1b[n][b][c] (bf16) = agg(h1), fp32 accumulate
__global__ __launch_bounds__(256) void k_agg128(
    const float* __restrict__ h1, const float* __restrict__ dinv,
    const int* __restrict__ csr_off, const int* __restrict__ csr_src,
    const float* __restrict__ csr_w, unsigned short* __restrict__ g1b) {
  int b = blockIdx.y;
  int nn = threadIdx.x >> 7, c = threadIdx.x & 127;
  int n = blockIdx.x * 2 + nn;
  float di = dinv[n];
  float acc = h1[((size_t)b * NN + n) * 128 + c] * di * di;
  int e0 = csr_off[n], e1 = csr_off[n + 1];
  for (int e = e0; e < e1; ++e)
    acc = fmaf(csr_w[e], h1[((size_t)b * NN + csr_src[e]) * 128 + c], acc);
  g1b[((size_t)n * NB + b) * 128 + c] = bf16_(acc);
}

// ---------------------------------------------------------------- h2T[f][b] = relu(g1 @ W2 + b2) via bf16 MFMA
// C[m=j][n=b] = sum_c A[j][c]*B[c][b]; A = W2T (regs, whole block), B = g1 node tile (LDS).
// block = 8 nodes, 256 thr = 4 waves; wave w owns mtiles 4w..4w+3 (j = 64w..64w+63).
// 16x16x32 frag layout: A[m=lane&15][k=quad*8+j], B[k=quad*8+j][n=lane&15],
// C col=lane&15 (b), row=quad*4+reg (j). LDS rows padded to 136 ushorts (16B-aligned, even bank spread).
__global__ __launch_bounds__(256) void k_gemm2b(
    const unsigned short* __restrict__ g1b, const unsigned short* __restrict__ W2T,
    const float* __restrict__ b2, float* __restrict__ h2T) {
  __shared__ unsigned short g1s[32][136];
  int t = threadIdx.x;
  int l = t & 63, w = t >> 6;
  int r = l & 15, ql = l >> 4;
  int n0 = blockIdx.x * 8;
  // A fragments: held in registers for the whole block (16 frags = 64 VGPRs)
  short8 afr[4][4];
#pragma unroll
  for (int mt = 0; mt < 4; ++mt)
#pragma unroll
    for (int kt = 0; kt < 4; ++kt)
      afr[mt][kt] = *(const short8*)&W2T[((w * 4 + mt) * 16 + r) * 128 + kt * 32 + ql * 8];
  // bias per (mt, reg)
  float bias[4][4];
#pragma unroll
  for (int mt = 0; mt < 4; ++mt)
#pragma unroll
    for (int rr = 0; rr < 4; ++rr)
      bias[mt][rr] = b2[(w * 4 + mt) * 16 + ql * 4 + rr];
  // prefetch node 0's g1 tile (8 KB = 512 x 16B chunks; thread t takes chunks t, t+256)
  uint4 pf0, pf1;
  {
    const uint4* src = (const uint4*)(g1b + (size_t)n0 * NB * 128);
    pf0 = src[t]; pf1 = src[t + 256];
  }
  for (int i = 0; i < 8; ++i) {
    __syncthreads();  // previous iteration's LDS readers done
    *(uint4*)&g1s[t >> 4][(t & 15) * 8] = pf0;
    {
      int i1 = t + 256;
      *(uint4*)&g1s[i1 >> 4][(i1 & 15) * 8] = pf1;
    }
    if (i + 1 < 8) {  // prefetch next node while this one computes
      const uint4* src = (const uint4*)(g1b + (size_t)(n0 + i + 1) * NB * 128);
      pf0 = src[t]; pf1 = src[t + 256];
    }
    __syncthreads();
    short8 bfr[2][4];
#pragma unroll
    for (int nt = 0; nt < 2; ++nt)
#pragma unroll
      for (int kt = 0; kt < 4; ++kt)
        bfr[nt][kt] = *(const short8*)&g1s[nt * 16 + r][kt * 32 + ql * 8];
    floatx4 acc[4][2];
#pragma unroll
    for (int mt = 0; mt < 4; ++mt)
#pragma unroll
      for (int nt = 0; nt < 2; ++nt) {
        floatx4 a = {0.0f, 0.0f, 0.0f, 0.0f};
#pragma unroll
        for (int kt = 0; kt < 4; ++kt)
          a = __builtin_amdgcn_mfma_f32_16x16x32_bf16(afr[mt][kt], bfr[nt][kt], a, 0, 0, 0);
        acc[mt][nt] = a;
      }
    size_t nodebase = (size_t)(n0 + i) * 256;
#pragma unroll
    for (int mt = 0; mt < 4; ++mt) {
#pragma unroll
      for (int rr = 0; rr < 4; ++rr) {
        int j = (w * 4 + mt) * 16 + ql * 4 + rr;
        float* dst = h2T + (nodebase + j) * 32 + r;
        dst[0]  = relu_(acc[mt][0][rr] + bias[mt][rr]);
        dst[16] = relu_(acc[mt][1][rr] + bias[mt][rr]);
      }
    }
  }
}

// ---------------------------------------------------------------- head: per-block (256 f) partials of feat@v1W, feat@advW
__global__ __launch_bounds__(256) void k_head(
    const float* __restrict__ h2T, const float* __restrict__ v1W,
    const float* __restrict__ advW, float* __restrict__ P) {
  __shared__ float s[8192];  // feat staging, then cross-wave reduction
  int t = threadIdx.x;
  size_t f0 = (size_t)blockIdx.x * 256;
  const float4* src = (const float4*)(h2T + f0 * 32);
  float4* dst = (float4*)s;
#pragma unroll
  for (int i = 0; i < 8; ++i) dst[t + 256 * i] = src[t + 256 * i];
  __syncthreads();
  int l = t & 63, w = t >> 6;
  bool adv_act = (l < 12);
  float accv[32], acca[32];
#pragma unroll
  for (int i = 0; i < 32; ++i) { accv[i] = 0.0f; acca[i] = 0.0f; }
  const float* v1p  = v1W  + (f0 + (size_t)w * 64) * 64 + l;
  const float* advp = advW + (f0 + (size_t)w * 64) * 12 + l;
#pragma unroll 2
  for (int i = 0; i < 64; ++i) {
    float wv = v1p[i * 64];
    float wa = adv_act ? advp[i * 12] : 0.0f;
    const float4* fr = (const float4*)&s[(w * 64 + i) * 32];
#pragma unroll
    for (int bb = 0; bb < 8; ++bb) {
      float4 h = fr[bb];  // LDS broadcast, conflict-free
      accv[4 * bb + 0] = fmaf(h.x, wv, accv[4 * bb + 0]);
      accv[4 * bb + 1] = fmaf(h.y, wv, accv[4 * bb + 1]);
      accv[4 * bb + 2] = fmaf(h.z, wv, accv[4 * bb + 2]);
      accv[4 * bb + 3] = fmaf(h.w, wv, accv[4 * bb + 3]);
      acca[4 * bb + 0] = fmaf(h.x, wa, acca[4 * bb + 0]);
      acca[4 * bb + 1] = fmaf(h.y, wa, acca[4 * bb + 1]);
      acca[4 * bb + 2] = fmaf(h.z, wa, acca[4 * bb + 2]);
      acca[4 * bb + 3] = fmaf(h.w, wa, acca[4 * bb + 3]);
    }
  }
  float* Pb = P + (size_t)blockIdx.x * NOUT_PAD;
  __syncthreads();
#pragma unroll
  for (int b = 0; b < 32; ++b) s[w * 2048 + b * 64 + l] = accv[b];
  __syncthreads();
  for (int o = t; o < 2048; o += 256)
    Pb[o] = s[o] + s[2048 + o] + s[4096 + o] + s[6144 + o];
  __syncthreads();
  if (adv_act) {
#pragma unroll
    for (int b = 0; b < 32; ++b) s[w * 384 + b * 12 + l] = acca[b];
  }
  __syncthreads();
  for (int o = t; o < 384; o += 256)
    Pb[2048 + o] = s[o] + s[384 + o] + s[768 + o] + s[1152 + o];
}

// ---------------------------------------------------------------- reduce stage 1: 4096 -> 64 rows
__global__ __launch_bounds__(256) void k_red1(const float* __restrict__ P,
                                              float* __restrict__ P1) {
  int r = blockIdx.x, t = threadIdx.x;
  const float* p = P + (size_t)r * 64 * NOUT_PAD;
  for (int o = t; o < NOUT_PAD; o += 256) {
    float sum = 0.0f;
    for (int k = 0; k < 64; ++k) sum += p[(size_t)k * NOUT_PAD + o];
    P1[r * NOUT_PAD + o] = sum;
  }
}

// ---------------------------------------------------------------- reduce stage 2: 64 -> 1
__global__ __launch_bounds__(256) void k_red2(const float* __restrict__ P1,
                                              float* __restrict__ S) {
  int o = blockIdx.x * 256 + threadIdx.x;
  if (o >= NOUT_PAD) return;
  float sum = 0.0f;
  for (int r = 0; r < 64; ++r) sum += P1[(size_t)r * NOUT_PAD + o];
  S[o] = sum;
}

// ---------------------------------------------------------------- final MLP + dueling combine
__global__ void k_final(const float* __restrict__ S,
                        const float* __restrict__ v1b, const float* __restrict__ v2W,
                        const float* __restrict__ v2b, const float* __restrict__ v3W,
                        const float* __restrict__ v3b, const float* __restrict__ advb,
                        float* __restrict__ out) {
  int b = blockIdx.x, t = threadIdx.x;
  __shared__ float v1s[64], v2s[64], as_[12];
  __shared__ float v3s;
  v1s[t] = relu_(S[b * 64 + t] + v1b[t]);
  if (t < 12) as_[t] = relu_(S[2048 + b * 12 + t] + advb[t]);
  __syncthreads();
  float acc = v2b[t];
  for (int k = 0; k < 64; ++k) acc = fmaf(v1s[k], v2W[k * 64 + t], acc);
  v2s[t] = relu_(acc);
  __syncthreads();
  if (t == 0) {
    float v3 = v3b[0];
    for (int j = 0; j < 64; ++j) v3 = fmaf(v2s[j], v3W[j], v3);
    v3s = v3;
  }
  __syncthreads();
  if (t < 12) {
    int h = t >> 2;
    float m = 0.25f * (as_[h * 4] + as_[h * 4 + 1] + as_[h * 4 + 2] + as_[h * 4 + 3]);
    out[b * 12 + t] = v3s + as_[t] - m;
  }
}

// ================================================================ launcher
extern "C" void kernel_launch(void* const* d_in, const int* in_sizes, int n_in,
                              void* d_out, int out_size, void* d_ws, size_t ws_size,
                              hipStream_t stream) {
  (void)in_sizes; (void)n_in; (void)out_size; (void)ws_size;
  const float* x    = (const float*)d_in[0];
  const int*   ei   = (const int*)d_in[1];
  const float* ew   = (const float*)d_in[2];
  const float* W1   = (const float*)d_in[3];
  const float* b1   = (const float*)d_in[4];
  const float* W2   = (const float*)d_in[5];
  const float* b2   = (const float*)d_in[6];
  const float* advW = (const float*)d_in[7];
  const float* advb = (const float*)d_in[8];
  const float* v1W  = (const float*)d_in[9];
  const float* v1b  = (const float*)d_in[10];
  const float* v2W  = (const float*)d_in[11];
  const float* v2b  = (const float*)d_in[12];
  const float* v3W  = (const float*)d_in[13];
  const float* v3b  = (const float*)d_in[14];
  float* out = (float*)d_out;

  const size_t MB = 1024 * 1024;
  char* w8 = (char*)d_ws;
  // small region [0, 4 MB)
  float* deg     = (float*)w8;                 // 4096
  float* dinv    = deg + 4096;                 // 4096
  int*   csr_off = (int*)(dinv + 4096);        // 4097 (padded to 4352)
  int*   cnt     = csr_off + 4352;             // 4096
  int*   fill    = cnt + 4096;                 // 4096
  int*   csr_src = fill + 4096;                // 16384
  float* csr_w   = (float*)(csr_src + NE);     // 16384
  float* S       = csr_w + NE;                 // 2432
  unsigned short* W2T = (unsigned short*)(S + 2432);  // 32768 ushorts
  // big buffers with lifetime-based overlays:
  //   h1  [4,68)    gemm1 -> agg128
  //   g0  [68,76)   agg16 -> gemm1
  //   h2T [4,132)   gemm2b (h1,g0 dead) -> head
  //   g1b [132,165) agg128 -> gemm2b  (bf16, 32 MB)
  //   P   [165,204) head -> red1
  //   P1  [204,205) red1 -> red2
  float* h1           = (float*)(w8 + 4 * MB);
  float* g0           = (float*)(w8 + 68 * MB);
  float* h2T          = (float*)(w8 + 4 * MB);
  unsigned short* g1b = (unsigned short*)(w8 + 132 * MB);
  float* P            = (float*)(w8 + 165 * MB);
  float* P1           = (float*)(w8 + 204 * MB);

  k_init  <<<16, 256, 0, stream>>>(deg, cnt, fill);
  k_edge1 <<<64, 256, 0, stream>>>(ei, ew, deg, cnt);
  k_scan  <<<1, 1024, 0, stream>>>(deg, dinv, cnt, csr_off);
  k_fill  <<<64, 256, 0, stream>>>(ei, ew, dinv, csr_off, fill, csr_src, csr_w);
  k_prep  <<<128, 256, 0, stream>>>(W2, W2T);
  k_agg16 <<<dim3(NN / 16, NB), 256, 0, stream>>>(x, dinv, csr_off, csr_src, csr_w, g0);
  k_gemm1 <<<dim3(NN / 16, NB), 256, 0, stream>>>(g0, W1, b1, h1);
  k_agg128<<<dim3(NN / 2, NB), 256, 0, stream>>>(h1, dinv, csr_off, csr_src, csr_w, g1b);
  k_gemm2b<<<NN / 8, 256, 0, stream>>>(g1b, W2T, b2, h2T);
  k_head  <<<NN, 256, 0, stream>>>(h2T, v1W, advW, P);
  k_red1  <<<64, 256, 0, stream>>>(P, P1);
  k_red2  <<<10, 256, 0, stream>>>(P1, S);
  k_final <<<NB, 64, 0, stream>>>(S, v1b, v2W, v2b, v3W, v3b, advb, out);
}